// Round 20
// baseline (607.766 us; speedup 1.0000x reference)
//
#include <hip/hip_runtime.h>
#include <cstdint>

using f32x4 = __attribute__((ext_vector_type(4))) float;
using s16x8 = __attribute__((ext_vector_type(8))) short;
typedef unsigned short u16;

typedef const __attribute__((address_space(1))) uint32_t* gptr_t;
typedef __attribute__((address_space(3))) uint32_t* lptr_t;

__device__ __forceinline__ u16 f2bf(float f) {
  union { float f; uint32_t u; } v; v.f = f;
  uint32_t r = v.u + 0x7FFFu + ((v.u >> 16) & 1u);  // RNE
  return (u16)(r >> 16);
}
__device__ __forceinline__ float bf2f(u16 b) {
  union { uint32_t u; float f; } v; v.u = ((uint32_t)b) << 16;
  return v.f;
}

// ---------------- k0: normalize prompts -> p_bf (bf16, padded to 1024 rows), ws[0,2MB)
__global__ __launch_bounds__(256) void k_prep_prompts(const float* __restrict__ prompts,
                                                      u16* __restrict__ p_bf) {
  const int r = blockIdx.x;
  const int t = threadIdx.x;
  if (r >= 1000) {
    if (t < 128) {
      s16x8 z = {0, 0, 0, 0, 0, 0, 0, 0};
      ((s16x8*)(p_bf + (size_t)r * 1024))[t] = z;
    }
    return;
  }
  float4 x = ((const float4*)(prompts + (size_t)r * 1024))[t];
  float ss = x.x * x.x + x.y * x.y + x.z * x.z + x.w * x.w;
  #pragma unroll
  for (int off = 32; off; off >>= 1) ss += __shfl_xor(ss, off);
  __shared__ float red[4];
  if ((t & 63) == 0) red[t >> 6] = ss;
  __syncthreads();
  float n = fmaxf(sqrtf(red[0] + red[1] + red[2] + red[3]), 1e-12f);
  float inv = 1.0f / n;
  u16* pb = p_bf + (size_t)r * 1024 + t * 4;
  pb[0] = f2bf(x.x * inv); pb[1] = f2bf(x.y * inv);
  pb[2] = f2bf(x.z * inv); pb[3] = f2bf(x.w * inv);
}

// ---------------- k0b: feat fp32 -> bf16 (scratch at start of PROBS region)
__global__ __launch_bounds__(256) void k_feat(const float* __restrict__ feat,
                                              u16* __restrict__ out) {
  const size_t stride = (size_t)gridDim.x * 256;
  const size_t n4 = 67108864ull / 4;
  for (size_t j = (size_t)blockIdx.x * 256 + threadIdx.x; j < n4; j += stride) {
    float4 x = ((const float4*)feat)[j];
    ushort4 o;
    o.x = f2bf(x.x); o.y = f2bf(x.y); o.z = f2bf(x.z); o.w = f2bf(x.w);
    ((ushort4*)out)[j] = o;
  }
}

// ---------------- k1: bf16 MFMA GEMM (256x256, 8 waves, ring+counted vmcnt+swizzle) with
// FUSED SCREEN epilogue: sims never hit HBM. Per row, per block: keep cols with stored
// value >= block_M2 - 0.25 (superset of the global screen since block_M2 <= global_M2),
// packed (bf16val<<16|col), <=16 slots, 0xFFFFFFFF pad -> cand[row][4][16] u32 (16 MB ws).
__global__ __launch_bounds__(512, 2) void k_sims(const u16* __restrict__ A,  // [65536][1024]
                                                 const u16* __restrict__ B,  // [1024][1024]
                                                 uint32_t* __restrict__ cand) {
  __shared__ union {
    struct { u16 As[4][2][128 * 32]; u16 Bs[4][2][128 * 32]; } ring;  // 128 KB
    u16 tile[256][260];                                               // 130 KB (pad 4 u16)
  } smem;
  const int bid = blockIdx.x;                        // grid 1024 = 8 * 128
  const int lg = (bid & 7) * 128 + (bid >> 3);       // XCD-grouping swizzle (bijective)
  const int bn = lg & 3;
  const int bm = lg >> 2;
  const int t = threadIdx.x;                         // 0..511
  const int wid = t >> 6, l = t & 63;
  const int wr = wid >> 2;
  const int wc = wid & 3;
  const int lrow = l & 15, lko = l >> 4;

  f32x4 acc[8][4];
  #pragma unroll
  for (int i = 0; i < 8; i++)
    #pragma unroll
    for (int j = 0; j < 4; j++) acc[i][j] = (f32x4){0.f, 0.f, 0.f, 0.f};

  const int srow = t >> 2;
  const int scol_sw = ((t & 3) * 8) ^ ((srow & 6) << 2);
  #define STAGE_A(db, h, kc)                                                              \
    __builtin_amdgcn_global_load_lds(                                                     \
        (gptr_t)(A + (size_t)(bm * 256 + (h) * 128 + srow) * 1024 + (kc) + scol_sw),      \
        (lptr_t)&smem.ring.As[db][h][t * 8], 16, 0, 0)
  #define STAGE_B(db, h, kc)                                                              \
    __builtin_amdgcn_global_load_lds(                                                     \
        (gptr_t)(B + (size_t)(bn * 256 + (h) * 128 + srow) * 1024 + (kc) + scol_sw),      \
        (lptr_t)&smem.ring.Bs[db][h][t * 8], 16, 0, 0)
  #define SWZ(row) (((row) * 32) + ((lko * 8) ^ (((row) & 6) << 2)))

  STAGE_A(0, 0, 0); STAGE_A(0, 1, 0); STAGE_B(0, 0, 0); STAGE_B(0, 1, 0);
  STAGE_A(1, 0, 32); STAGE_A(1, 1, 32); STAGE_B(1, 0, 32); STAGE_B(1, 1, 32);

  const int hB = wc >> 1, rB = (wc & 1) * 64;
  for (int j = 0; j < 32; ++j) {
    const int p = j & 3;
    if (j == 31) asm volatile("s_waitcnt vmcnt(0)" ::: "memory");
    else         asm volatile("s_waitcnt vmcnt(4)" ::: "memory");
    __builtin_amdgcn_s_barrier();
    s16x8 b[4];
    #pragma unroll
    for (int m2 = 0; m2 < 2; ++m2) {
      s16x8 a[4];
      #pragma unroll
      for (int i = 0; i < 4; ++i) {
        const int ar = m2 * 64 + i * 16 + lrow;
        a[i] = *(const s16x8*)&smem.ring.As[p][wr][SWZ(ar)];
      }
      if (m2 == 0) {
        #pragma unroll
        for (int ni = 0; ni < 4; ++ni) {
          const int br = rB + ni * 16 + lrow;
          b[ni] = *(const s16x8*)&smem.ring.Bs[p][hB][SWZ(br)];
        }
      }
      if (j < 30) {
        const int db = (j + 2) & 3, kn = (j + 2) * 32;
        if (m2 == 0) { STAGE_A(db, 0, kn); STAGE_A(db, 1, kn); }
        else         { STAGE_B(db, 0, kn); STAGE_B(db, 1, kn); }
      }
      __builtin_amdgcn_s_setprio(1);
      #pragma unroll
      for (int i = 0; i < 4; ++i)
        #pragma unroll
        for (int ni = 0; ni < 4; ++ni)
          acc[m2 * 4 + i][ni] =
              __builtin_amdgcn_mfma_f32_16x16x32_bf16(a[i], b[ni], acc[m2 * 4 + i][ni], 0, 0, 0);
      __builtin_amdgcn_s_setprio(0);
      __builtin_amdgcn_s_barrier();
    }
  }
  #undef STAGE_A
  #undef STAGE_B
  #undef SWZ
  // ---- epilogue A: acc -> LDS tile (bf16, row-major)
  __syncthreads();
  const int rbase = (l >> 4) * 4;
  const int trow0 = wr * 128, tcol0 = wc * 64;
  #pragma unroll
  for (int mi = 0; mi < 8; ++mi)
    #pragma unroll
    for (int ni = 0; ni < 4; ++ni)
      #pragma unroll
      for (int jj = 0; jj < 4; ++jj)
        smem.tile[trow0 + mi * 16 + rbase + jj][tcol0 + ni * 16 + lrow] = f2bf(acc[mi][ni][jj]);
  __syncthreads();
  // ---- epilogue B: per-row block-local screen -> compact candidate list (wave w: 32 rows)
  const float NEGF = -3.0e38f;
  #pragma unroll 1
  for (int rr = 0; rr < 32; ++rr) {
    const int r = wid * 32 + rr;
    const uint64_t pk = *(const uint64_t*)&smem.tile[r][l * 4];  // 4 bf16, 8-B aligned
    const int cbase = bn * 256 + l * 4;
    float f0 = (cbase + 0 < 1000) ? bf2f((u16)(pk)) : NEGF;
    float f1 = (cbase + 1 < 1000) ? bf2f((u16)(pk >> 16)) : NEGF;
    float f2 = (cbase + 2 < 1000) ? bf2f((u16)(pk >> 32)) : NEGF;
    float f3 = (cbase + 3 < 1000) ? bf2f((u16)(pk >> 48)) : NEGF;
    // per-lane top-2 (static)
    float a1 = f0, a2 = NEGF;
    { bool g = f1 > a1; a2 = g ? a1 : fmaxf(a2, f1); a1 = g ? f1 : a1; }
    { bool g = f2 > a1; a2 = g ? a1 : fmaxf(a2, f2); a1 = g ? f2 : a1; }
    { bool g = f3 > a1; a2 = g ? a1 : fmaxf(a2, f3); a1 = g ? f3 : a1; }
    #pragma unroll
    for (int off = 32; off; off >>= 1) {
      float b1 = __shfl_xor(a1, off), b2 = __shfl_xor(a2, off);
      float m1 = fmaxf(a1, b1);
      float m2v = fmaxf(fminf(a1, b1), fmaxf(a2, b2));
      a1 = m1; a2 = m2v;
    }
    const float T = a2 - 0.25f;          // block-local margin (superset of global screen)
    uint32_t m4 = 0;
    if (f0 >= T) m4 |= 1u;
    if (f1 >= T) m4 |= 2u;
    if (f2 >= T) m4 |= 4u;
    if (f3 >= T) m4 |= 8u;
    uint32_t myword = 0xFFFFFFFFu;       // pad: col 0xFFFF (invalid)
    #pragma unroll 1
    for (int it = 0; it < 16; ++it) {
      unsigned long long act = __ballot(m4 != 0);
      if (!act) break;
      int ln = (int)__ffsll(act) - 1;
      int fj = __ffs(m4) - 1;
      uint32_t vbits = (uint32_t)((pk >> (16 * fj)) & 0xFFFFull);
      uint32_t wd = (vbits << 16) | (uint32_t)(cbase + fj);
      uint32_t wdb = __shfl(wd, ln);
      if (l == it) myword = wdb;
      if (l == ln) m4 &= (m4 - 1);
    }
    if (l < 16) cand[(size_t)(bm * 256 + r) * 64 + bn * 16 + l] = myword;
  }
}

// ---------------- k2: candidate merge + exact rescore + top-2 -> probs + resc/resw.
// Global stored M1/M2 derived exactly from candidate values (both global top-2 stored
// cols are in their blocks' lists) -> same survivor set & numerics as rounds 8-19.
__global__ __launch_bounds__(256) void k_topk(const float* __restrict__ feat,
                                              const float* __restrict__ prompts,
                                              const uint32_t* __restrict__ cand,
                                              int2* __restrict__ resc,
                                              float2* __restrict__ resw,
                                              float* __restrict__ probs) {
  const int l = threadIdx.x & 63;
  const int row = blockIdx.x * 4 + (threadIdx.x >> 6);
  const float NEG = -3.0e38f;
  // lane l: candidate slot l (block l>>4, slot l&15) — coalesced 256 B/wave
  uint32_t wd = cand[(size_t)row * 64 + l];
  int col = (int)(wd & 0xFFFFu);
  float val = (col < 1000) ? bf2f((u16)(wd >> 16)) : NEG;
  // exact global stored top-2 over candidates
  float a1 = val, a2 = NEG;
  #pragma unroll
  for (int off = 32; off; off >>= 1) {
    float b1 = __shfl_xor(a1, off), b2 = __shfl_xor(a2, off);
    float m1 = fmaxf(a1, b1);
    float m2 = fmaxf(fminf(a1, b1), fmaxf(a2, b2));
    a1 = m1; a2 = m2;
  }
  const float T = a2 - 0.25f;          // stored-scale margin (round-8 analysis)
  const bool ok = (col < 1000) && (val >= T);
  // feat row + norm
  const int base = l * 16;
  float q[16];
  const float4* fr = (const float4*)(feat + (size_t)row * 1024 + base);
  #pragma unroll
  for (int g = 0; g < 4; g++) {
    float4 x = fr[g];
    q[g * 4 + 0] = x.x; q[g * 4 + 1] = x.y; q[g * 4 + 2] = x.z; q[g * 4 + 3] = x.w;
  }
  float qq = 0.f;
  #pragma unroll
  for (int e = 0; e < 16; e++) qq += q[e] * q[e];
  #pragma unroll
  for (int off = 32; off; off >>= 1) qq += __shfl_xor(qq, off);
  float rn = 1.0f / fmaxf(sqrtf(qq), 1e-12f);
  // survivor loop over a single wave-uniform ballot mask (1 candidate per lane)
  float s1 = NEG, s2 = NEG;
  int c1 = 0x40000000, c2 = 0x40000000;
  unsigned long long actmask = __ballot(ok);
  while (actmask) {
    int ln = (int)__ffsll(actmask) - 1;
    actmask &= actmask - 1;            // wave-uniform
    int bc = __shfl(col, ln);
    bc = (bc < 1000) ? bc : 999;
    const float4* pr = (const float4*)(prompts + (size_t)bc * 1024 + base);
    float d = 0.f, nn = 0.f;
    #pragma unroll
    for (int g = 0; g < 4; g++) {
      float4 x = pr[g];
      d += q[g * 4 + 0] * x.x; d += q[g * 4 + 1] * x.y;
      d += q[g * 4 + 2] * x.z; d += q[g * 4 + 3] * x.w;
      nn += x.x * x.x + x.y * x.y + x.z * x.z + x.w * x.w;
    }
    #pragma unroll
    for (int off = 32; off; off >>= 1) {
      d += __shfl_xor(d, off);
      nn += __shfl_xor(nn, off);
    }
    float sc = d * rn / fmaxf(sqrtf(nn), 1e-12f);
    bool b1w = (sc > s1) || (sc == s1 && bc < c1);
    bool b2w = (sc > s2) || (sc == s2 && bc < c2);
    if (b1w) { s2 = s1; c2 = c1; s1 = sc; c1 = bc; }
    else if (b2w) { s2 = sc; c2 = bc; }
  }
  float e = expf(fminf(s2 - s1, 0.0f) * (1.0f / 0.07f));  // (0,1]
  float w1 = 1.0f / (1.0f + e);
  float w2 = e / (1.0f + e);
  // probs row write (strided, coalesced): zeros + two weights (overwrites dead feat_bf)
  float* prow = probs + (size_t)row * 1000;
  #pragma unroll
  for (int j = 0; j < 16; j++) {
    int c = l + 64 * j;
    if (c < 1000) prow[c] = (c == c1) ? w1 : ((c == c2) ? w2 : 0.0f);
  }
  if (l == 0) {
    resc[row] = make_int2(c1, c2);
    resw[row] = make_float2(w1, w2);
  }
}

// ---------------- k3: mixed = w1*P1 + w2*P2 (one block per row; mixed region is clean)
__global__ __launch_bounds__(256) void k_write2(const float* __restrict__ prompts,
                                                const int2* __restrict__ resc,
                                                const float2* __restrict__ resw,
                                                float* __restrict__ mixed) {
  const int row = blockIdx.x;
  const int t = threadIdx.x;
  int2 cc = resc[row];
  float2 ww = resw[row];
  float4 a = ((const float4*)(prompts + (size_t)cc.x * 1024))[t];
  float4 b = ((const float4*)(prompts + (size_t)cc.y * 1024))[t];
  float4 o;
  o.x = ww.x * a.x + ww.y * b.x;
  o.y = ww.x * a.y + ww.y * b.y;
  o.z = ww.x * a.z + ww.y * b.z;
  o.w = ww.x * a.w + ww.y * b.w;
  ((float4*)(mixed + (size_t)row * 1024))[t] = o;
}

extern "C" void kernel_launch(void* const* d_in, const int* in_sizes, int n_in,
                              void* d_out, int out_size, void* d_ws, size_t ws_size,
                              hipStream_t stream) {
  int fi = 0, pi = 1;
  for (int i = 0; i < n_in; i++) {
    if (in_sizes[i] == 67108864) fi = i;
    else if (in_sizes[i] == 1024000) pi = i;
  }
  const float* feat = (const float*)d_in[fi];
  const float* prompts = (const float*)d_in[pi];

  float* mixed = (float*)d_out;                 // [65536*1024] f32 (output 0)
  float* probs = mixed + 67108864ull;           // [65536*1000] f32 (output 1)

  // ws: [0,2MB) p_bf; [2,2.5MB) resc; [2.5,3MB) resw; [3,19MB) cand (65536 x 64 u32).
  // ws_size >= 128 MiB (verified round 9: big_ws branch executed).
  u16* p_bf = (u16*)d_ws;
  int2* resc = (int2*)((char*)d_ws + (2ull << 20));
  float2* resw = (float2*)((char*)d_ws + (2ull << 20) + (512ull << 10));
  uint32_t* cand = (uint32_t*)((char*)d_ws + (3ull << 20));

  // feat_bf at start of PROBS region (read by k_sims, overwritten by k_topk's probs).
  // mixed region stays clean (sims never materialized).
  u16* feat_bf = (u16*)probs;

  hipLaunchKernelGGL(k_prep_prompts, dim3(1024), dim3(256), 0, stream, prompts, p_bf);
  hipLaunchKernelGGL(k_feat, dim3(2048), dim3(256), 0, stream, feat, feat_bf);
  hipLaunchKernelGGL(k_sims, dim3(1024), dim3(512), 0, stream, feat_bf, p_bf, cand);
  hipLaunchKernelGGL(k_topk, dim3(16384), dim3(256), 0, stream,
                     feat, prompts, cand, resc, resw, probs);
  hipLaunchKernelGGL(k_write2, dim3(65536), dim3(256), 0, stream, prompts, resc, resw, mixed);
}

// Round 21
// 497.693 us; speedup vs baseline: 1.2212x; 1.2212x over previous
//
#include <hip/hip_runtime.h>
#include <cstdint>

using f32x4 = __attribute__((ext_vector_type(4))) float;
using s16x8 = __attribute__((ext_vector_type(8))) short;
typedef unsigned short u16;

typedef const __attribute__((address_space(1))) uint32_t* gptr_t;
typedef __attribute__((address_space(3))) uint32_t* lptr_t;

__device__ __forceinline__ u16 f2bf(float f) {
  union { float f; uint32_t u; } v; v.f = f;
  uint32_t r = v.u + 0x7FFFu + ((v.u >> 16) & 1u);  // RNE
  return (u16)(r >> 16);
}
__device__ __forceinline__ float bf2f(u16 b) {
  union { uint32_t u; float f; } v; v.u = ((uint32_t)b) << 16;
  return v.f;
}

// ---------------- k0: normalize prompts -> p_bf (bf16, padded to 1024 rows), ws[0,2MB)
__global__ __launch_bounds__(256) void k_prep_prompts(const float* __restrict__ prompts,
                                                      u16* __restrict__ p_bf) {
  const int r = blockIdx.x;
  const int t = threadIdx.x;
  if (r >= 1000) {
    if (t < 128) {
      s16x8 z = {0, 0, 0, 0, 0, 0, 0, 0};
      ((s16x8*)(p_bf + (size_t)r * 1024))[t] = z;
    }
    return;
  }
  float4 x = ((const float4*)(prompts + (size_t)r * 1024))[t];
  float ss = x.x * x.x + x.y * x.y + x.z * x.z + x.w * x.w;
  #pragma unroll
  for (int off = 32; off; off >>= 1) ss += __shfl_xor(ss, off);
  __shared__ float red[4];
  if ((t & 63) == 0) red[t >> 6] = ss;
  __syncthreads();
  float n = fmaxf(sqrtf(red[0] + red[1] + red[2] + red[3]), 1e-12f);
  float inv = 1.0f / n;
  u16* pb = p_bf + (size_t)r * 1024 + t * 4;
  pb[0] = f2bf(x.x * inv); pb[1] = f2bf(x.y * inv);
  pb[2] = f2bf(x.z * inv); pb[3] = f2bf(x.w * inv);
}

// ---------------- k0b: feat fp32 -> bf16 (scratch at start of PROBS region)
__global__ __launch_bounds__(256) void k_feat(const float* __restrict__ feat,
                                              u16* __restrict__ out) {
  const size_t stride = (size_t)gridDim.x * 256;
  const size_t n4 = 67108864ull / 4;
  for (size_t j = (size_t)blockIdx.x * 256 + threadIdx.x; j < n4; j += stride) {
    float4 x = ((const float4*)feat)[j];
    ushort4 o;
    o.x = f2bf(x.x); o.y = f2bf(x.y); o.z = f2bf(x.z); o.w = f2bf(x.w);
    ((ushort4*)out)[j] = o;
  }
}

// ---------------- k1: bf16 MFMA GEMM — 256x256, 8 waves, BK=32, 4-deep ring, counted vmcnt,
// setprio, T2 XOR-swizzle + LDS-transpose epilogue (coalesced C stores). Round-19 best.
__global__ __launch_bounds__(512, 2) void k_sims(const u16* __restrict__ A,  // [65536][1024]
                                                 const u16* __restrict__ B,  // [1024][1024]
                                                 u16* __restrict__ C) {      // [65536][1000]
  __shared__ union {
    struct { u16 As[4][2][128 * 32]; u16 Bs[4][2][128 * 32]; } ring;  // 128 KB
    u16 tile[256][260];                                               // 130 KB (pad 4 u16)
  } smem;
  const int bid = blockIdx.x;                        // grid 1024 = 8 * 128
  const int lg = (bid & 7) * 128 + (bid >> 3);       // XCD-grouping swizzle (bijective)
  const int bn = lg & 3;
  const int bm = lg >> 2;
  const int t = threadIdx.x;                         // 0..511
  const int wid = t >> 6, l = t & 63;
  const int wr = wid >> 2;                           // wave row-half (0..1)
  const int wc = wid & 3;                            // wave col quarter (0..3)
  const int lrow = l & 15, lko = l >> 4;

  f32x4 acc[8][4];
  #pragma unroll
  for (int i = 0; i < 8; i++)
    #pragma unroll
    for (int j = 0; j < 4; j++) acc[i][j] = (f32x4){0.f, 0.f, 0.f, 0.f};

  const int srow = t >> 2;
  const int scol_sw = ((t & 3) * 8) ^ ((srow & 6) << 2);
  #define STAGE_A(db, h, kc)                                                              \
    __builtin_amdgcn_global_load_lds(                                                     \
        (gptr_t)(A + (size_t)(bm * 256 + (h) * 128 + srow) * 1024 + (kc) + scol_sw),      \
        (lptr_t)&smem.ring.As[db][h][t * 8], 16, 0, 0)
  #define STAGE_B(db, h, kc)                                                              \
    __builtin_amdgcn_global_load_lds(                                                     \
        (gptr_t)(B + (size_t)(bn * 256 + (h) * 128 + srow) * 1024 + (kc) + scol_sw),      \
        (lptr_t)&smem.ring.Bs[db][h][t * 8], 16, 0, 0)
  #define SWZ(row) (((row) * 32) + ((lko * 8) ^ (((row) & 6) << 2)))

  STAGE_A(0, 0, 0); STAGE_A(0, 1, 0); STAGE_B(0, 0, 0); STAGE_B(0, 1, 0);
  STAGE_A(1, 0, 32); STAGE_A(1, 1, 32); STAGE_B(1, 0, 32); STAGE_B(1, 1, 32);

  const int hB = wc >> 1, rB = (wc & 1) * 64;
  for (int j = 0; j < 32; ++j) {
    const int p = j & 3;
    if (j == 31) asm volatile("s_waitcnt vmcnt(0)" ::: "memory");
    else         asm volatile("s_waitcnt vmcnt(4)" ::: "memory");
    __builtin_amdgcn_s_barrier();
    s16x8 b[4];
    #pragma unroll
    for (int m2 = 0; m2 < 2; ++m2) {
      s16x8 a[4];
      #pragma unroll
      for (int i = 0; i < 4; ++i) {
        const int ar = m2 * 64 + i * 16 + lrow;
        a[i] = *(const s16x8*)&smem.ring.As[p][wr][SWZ(ar)];
      }
      if (m2 == 0) {
        #pragma unroll
        for (int ni = 0; ni < 4; ++ni) {
          const int br = rB + ni * 16 + lrow;
          b[ni] = *(const s16x8*)&smem.ring.Bs[p][hB][SWZ(br)];
        }
      }
      if (j < 30) {
        const int db = (j + 2) & 3, kn = (j + 2) * 32;
        if (m2 == 0) { STAGE_A(db, 0, kn); STAGE_A(db, 1, kn); }
        else         { STAGE_B(db, 0, kn); STAGE_B(db, 1, kn); }
      }
      __builtin_amdgcn_s_setprio(1);
      #pragma unroll
      for (int i = 0; i < 4; ++i)
        #pragma unroll
        for (int ni = 0; ni < 4; ++ni)
          acc[m2 * 4 + i][ni] =
              __builtin_amdgcn_mfma_f32_16x16x32_bf16(a[i], b[ni], acc[m2 * 4 + i][ni], 0, 0, 0);
      __builtin_amdgcn_s_setprio(0);
      __builtin_amdgcn_s_barrier();
    }
  }
  #undef STAGE_A
  #undef STAGE_B
  #undef SWZ
  // ---- epilogue: acc -> LDS tile (bf16) -> coalesced ushort4 stores.
  __syncthreads();
  const int rbase = (l >> 4) * 4;
  const int trow0 = wr * 128, tcol0 = wc * 64;
  #pragma unroll
  for (int mi = 0; mi < 8; ++mi)
    #pragma unroll
    for (int ni = 0; ni < 4; ++ni)
      #pragma unroll
      for (int jj = 0; jj < 4; ++jj)
        smem.tile[trow0 + mi * 16 + rbase + jj][tcol0 + ni * 16 + lrow] = f2bf(acc[mi][ni][jj]);
  __syncthreads();
  #pragma unroll 1
  for (int q = t; q < 256 * 64; q += 512) {
    const int r = q >> 6;                 // row 0..255
    const int cl = (q & 63) * 4;          // local col chunk (4 u16)
    const int gcol = bn * 256 + cl;
    if (gcol < 1000) {
      ushort4 v = *(const ushort4*)&smem.tile[r][cl];   // 8-B aligned (row stride 520 B)
      *(ushort4*)&C[(size_t)(bm * 256 + r) * 1000 + gcol] = v;
    }
  }
}

// ---------------- k2: round-8/17 fused screen + serial exact rescore + inline probs.
__global__ __launch_bounds__(256) void k_topk(const float* __restrict__ feat,
                                              const float* __restrict__ prompts,
                                              const u16* __restrict__ sims,
                                              int2* __restrict__ resc,
                                              float2* __restrict__ resw,
                                              float* __restrict__ probs) {
  const int l = threadIdx.x & 63;
  const int row = blockIdx.x * 4 + (threadIdx.x >> 6);
  const u16* srow = sims + (size_t)row * 1000;
  const float NEG = -3.0e38f;
  float s[16];
  #pragma unroll
  for (int j = 0; j < 8; j++) {
    int c = 2 * l + 128 * j;
    if (c + 1 < 1000) {
      uint32_t v = *(const uint32_t*)(srow + c);
      s[2 * j] = bf2f((u16)(v & 0xFFFFu));
      s[2 * j + 1] = bf2f((u16)(v >> 16));
    } else {
      s[2 * j] = (c < 1000) ? bf2f(srow[c]) : NEG;
      s[2 * j + 1] = NEG;
    }
  }
  float a1 = NEG, a2 = NEG;
  #pragma unroll
  for (int j = 0; j < 16; j++) {
    float v = s[j];
    bool g1 = v > a1;
    a2 = g1 ? a1 : fmaxf(a2, v);
    a1 = g1 ? v : a1;
  }
  #pragma unroll
  for (int off = 32; off; off >>= 1) {
    float b1 = __shfl_xor(a1, off), b2 = __shfl_xor(a2, off);
    float m1 = fmaxf(a1, b1);
    float m2 = fmaxf(fminf(a1, b1), fmaxf(a2, b2));
    a1 = m1; a2 = m2;
  }
  const float T = a2 - 0.25f;   // stored-scale margin (round-8 analysis)
  uint32_t mask = 0;
  #pragma unroll
  for (int j = 0; j < 16; j++) {
    int c = 2 * l + 128 * (j >> 1) + (j & 1);
    if (c < 1000 && s[j] >= T) mask |= (1u << j);
  }
  const int base = l * 16;
  float q[16];
  const float4* fr = (const float4*)(feat + (size_t)row * 1024 + base);
  #pragma unroll
  for (int g = 0; g < 4; g++) {
    float4 x = fr[g];
    q[g * 4 + 0] = x.x; q[g * 4 + 1] = x.y; q[g * 4 + 2] = x.z; q[g * 4 + 3] = x.w;
  }
  float qq = 0.f;
  #pragma unroll
  for (int e = 0; e < 16; e++) qq += q[e] * q[e];
  #pragma unroll
  for (int off = 32; off; off >>= 1) qq += __shfl_xor(qq, off);
  float rn = 1.0f / fmaxf(sqrtf(qq), 1e-12f);
  float s1 = NEG, s2 = NEG;
  int c1 = 0x40000000, c2 = 0x40000000;
  while (true) {
    unsigned long long act = __ballot(mask != 0);
    if (!act) break;
    int ln = (int)__ffsll(act) - 1;
    int fj = __ffs(mask) - 1;
    int myc = 2 * l + 128 * ((fj >> 1) & 7) + (fj & 1);
    int bc = __shfl(myc, ln);
    if (l == ln) mask &= (mask - 1);
    bc = (bc < 1000) ? bc : 999;
    const float4* pr = (const float4*)(prompts + (size_t)bc * 1024 + base);
    float d = 0.f, nn = 0.f;
    #pragma unroll
    for (int g = 0; g < 4; g++) {
      float4 x = pr[g];
      d += q[g * 4 + 0] * x.x; d += q[g * 4 + 1] * x.y;
      d += q[g * 4 + 2] * x.z; d += q[g * 4 + 3] * x.w;
      nn += x.x * x.x + x.y * x.y + x.z * x.z + x.w * x.w;
    }
    #pragma unroll
    for (int off = 32; off; off >>= 1) {
      d += __shfl_xor(d, off);
      nn += __shfl_xor(nn, off);
    }
    float sc = d * rn / fmaxf(sqrtf(nn), 1e-12f);
    bool b1w = (sc > s1) || (sc == s1 && bc < c1);
    bool b2w = (sc > s2) || (sc == s2 && bc < c2);
    if (b1w) { s2 = s1; c2 = c1; s1 = sc; c1 = bc; }
    else if (b2w) { s2 = sc; c2 = bc; }
  }
  float e = expf(fminf(s2 - s1, 0.0f) * (1.0f / 0.07f));  // (0,1]
  float w1 = 1.0f / (1.0f + e);
  float w2 = e / (1.0f + e);
  float* prow = probs + (size_t)row * 1000;
  #pragma unroll
  for (int j = 0; j < 16; j++) {
    int c = l + 64 * j;
    if (c < 1000) prow[c] = (c == c1) ? w1 : ((c == c2) ? w2 : 0.0f);
  }
  if (l == 0) {
    resc[row] = make_int2(c1, c2);
    resw[row] = make_float2(w1, w2);
  }
}

// ---------------- k3: mixed = w1*P1 + w2*P2 (one block per row; overwrites dead sims scratch)
__global__ __launch_bounds__(256) void k_write2(const float* __restrict__ prompts,
                                                const int2* __restrict__ resc,
                                                const float2* __restrict__ resw,
                                                float* __restrict__ mixed) {
  const int row = blockIdx.x;
  const int t = threadIdx.x;
  int2 cc = resc[row];
  float2 ww = resw[row];
  float4 a = ((const float4*)(prompts + (size_t)cc.x * 1024))[t];
  float4 b = ((const float4*)(prompts + (size_t)cc.y * 1024))[t];
  float4 o;
  o.x = ww.x * a.x + ww.y * b.x;
  o.y = ww.x * a.y + ww.y * b.y;
  o.z = ww.x * a.z + ww.y * b.z;
  o.w = ww.x * a.w + ww.y * b.w;
  ((float4*)(mixed + (size_t)row * 1024))[t] = o;
}

extern "C" void kernel_launch(void* const* d_in, const int* in_sizes, int n_in,
                              void* d_out, int out_size, void* d_ws, size_t ws_size,
                              hipStream_t stream) {
  int fi = 0, pi = 1;
  for (int i = 0; i < n_in; i++) {
    if (in_sizes[i] == 67108864) fi = i;
    else if (in_sizes[i] == 1024000) pi = i;
  }
  const float* feat = (const float*)d_in[fi];
  const float* prompts = (const float*)d_in[pi];

  float* mixed = (float*)d_out;                 // [65536*1024] f32 (output 0)
  float* probs = mixed + 67108864ull;           // [65536*1000] f32 (output 1)

  // ws: [0,2MB) p_bf; [2,2.5MB) resc; [2.5,3MB) resw
  u16* p_bf = (u16*)d_ws;
  int2* resc = (int2*)((char*)d_ws + (2ull << 20));
  float2* resw = (float2*)((char*)d_ws + (2ull << 20) + (512ull << 10));

  // Memory plan (row-exclusive aliasing, stream-ordered):
  //   bf16 sims  at start of MIXED region (read by k_topk, overwritten by k_write2)
  //   bf16 feat  at start of PROBS region (read by k_sims, overwritten by k_topk's probs)
  u16* sims = (u16*)mixed;
  u16* feat_bf = (u16*)probs;

  hipLaunchKernelGGL(k_prep_prompts, dim3(1024), dim3(256), 0, stream, prompts, p_bf);
  hipLaunchKernelGGL(k_feat, dim3(2048), dim3(256), 0, stream, feat, feat_bf);
  hipLaunchKernelGGL(k_sims, dim3(1024), dim3(512), 0, stream, feat_bf, p_bf, sims);
  hipLaunchKernelGGL(k_topk, dim3(16384), dim3(256), 0, stream, feat, prompts, sims, resc, resw, probs);
  hipLaunchKernelGGL(k_write2, dim3(65536), dim3(256), 0, stream, prompts, resc, resw, mixed);
}

// Round 22
// 496.152 us; speedup vs baseline: 1.2250x; 1.0031x over previous
//
#include <hip/hip_runtime.h>
#include <cstdint>

using f32x4 = __attribute__((ext_vector_type(4))) float;
using s16x8 = __attribute__((ext_vector_type(8))) short;
typedef unsigned short u16;

typedef const __attribute__((address_space(1))) uint32_t* gptr_t;
typedef __attribute__((address_space(3))) uint32_t* lptr_t;

__device__ __forceinline__ u16 f2bf(float f) {
  union { float f; uint32_t u; } v; v.f = f;
  uint32_t r = v.u + 0x7FFFu + ((v.u >> 16) & 1u);  // RNE
  return (u16)(r >> 16);
}
__device__ __forceinline__ float bf2f(u16 b) {
  union { uint32_t u; float f; } v; v.u = ((uint32_t)b) << 16;
  return v.f;
}

// ---------------- k0: normalize prompts -> p_bf (bf16, padded to 1024 rows), ws[0,2MB)
__global__ __launch_bounds__(256) void k_prep_prompts(const float* __restrict__ prompts,
                                                      u16* __restrict__ p_bf) {
  const int r = blockIdx.x;
  const int t = threadIdx.x;
  if (r >= 1000) {
    if (t < 128) {
      s16x8 z = {0, 0, 0, 0, 0, 0, 0, 0};
      ((s16x8*)(p_bf + (size_t)r * 1024))[t] = z;
    }
    return;
  }
  float4 x = ((const float4*)(prompts + (size_t)r * 1024))[t];
  float ss = x.x * x.x + x.y * x.y + x.z * x.z + x.w * x.w;
  #pragma unroll
  for (int off = 32; off; off >>= 1) ss += __shfl_xor(ss, off);
  __shared__ float red[4];
  if ((t & 63) == 0) red[t >> 6] = ss;
  __syncthreads();
  float n = fmaxf(sqrtf(red[0] + red[1] + red[2] + red[3]), 1e-12f);
  float inv = 1.0f / n;
  u16* pb = p_bf + (size_t)r * 1024 + t * 4;
  pb[0] = f2bf(x.x * inv); pb[1] = f2bf(x.y * inv);
  pb[2] = f2bf(x.z * inv); pb[3] = f2bf(x.w * inv);
}

// ---------------- k0b: feat fp32 -> bf16 (scratch at start of PROBS region)
__global__ __launch_bounds__(256) void k_feat(const float* __restrict__ feat,
                                              u16* __restrict__ out) {
  const size_t stride = (size_t)gridDim.x * 256;
  const size_t n4 = 67108864ull / 4;
  for (size_t j = (size_t)blockIdx.x * 256 + threadIdx.x; j < n4; j += stride) {
    float4 x = ((const float4*)feat)[j];
    ushort4 o;
    o.x = f2bf(x.x); o.y = f2bf(x.y); o.z = f2bf(x.z); o.w = f2bf(x.w);
    ((ushort4*)out)[j] = o;
  }
}

// ---------------- k1: bf16 MFMA GEMM — 256x256, 8 waves, BK=32, 4-deep ring, counted vmcnt,
// setprio, T2 XOR-swizzle, LDS-transpose epilogue. ONE barrier per K-tile (trailing
// barriers deleted: stage target buf (j+2)&3 was last read at K-tile j-2, separated from
// this overwrite by the entry barriers of j-1 and j — WAR holds without per-m2 syncs).
__global__ __launch_bounds__(512, 2) void k_sims(const u16* __restrict__ A,  // [65536][1024]
                                                 const u16* __restrict__ B,  // [1024][1024]
                                                 u16* __restrict__ C) {      // [65536][1000]
  __shared__ union {
    struct { u16 As[4][2][128 * 32]; u16 Bs[4][2][128 * 32]; } ring;  // 128 KB
    u16 tile[256][260];                                               // 130 KB (pad 4 u16)
  } smem;
  const int bid = blockIdx.x;                        // grid 1024 = 8 * 128
  const int lg = (bid & 7) * 128 + (bid >> 3);       // XCD-grouping swizzle (bijective)
  const int bn = lg & 3;
  const int bm = lg >> 2;
  const int t = threadIdx.x;                         // 0..511
  const int wid = t >> 6, l = t & 63;
  const int wr = wid >> 2;                           // wave row-half (0..1)
  const int wc = wid & 3;                            // wave col quarter (0..3)
  const int lrow = l & 15, lko = l >> 4;

  f32x4 acc[8][4];
  #pragma unroll
  for (int i = 0; i < 8; i++)
    #pragma unroll
    for (int j = 0; j < 4; j++) acc[i][j] = (f32x4){0.f, 0.f, 0.f, 0.f};

  const int srow = t >> 2;
  const int scol_sw = ((t & 3) * 8) ^ ((srow & 6) << 2);
  #define STAGE_A(db, h, kc)                                                              \
    __builtin_amdgcn_global_load_lds(                                                     \
        (gptr_t)(A + (size_t)(bm * 256 + (h) * 128 + srow) * 1024 + (kc) + scol_sw),      \
        (lptr_t)&smem.ring.As[db][h][t * 8], 16, 0, 0)
  #define STAGE_B(db, h, kc)                                                              \
    __builtin_amdgcn_global_load_lds(                                                     \
        (gptr_t)(B + (size_t)(bn * 256 + (h) * 128 + srow) * 1024 + (kc) + scol_sw),      \
        (lptr_t)&smem.ring.Bs[db][h][t * 8], 16, 0, 0)
  #define SWZ(row) (((row) * 32) + ((lko * 8) ^ (((row) & 6) << 2)))

  STAGE_A(0, 0, 0); STAGE_A(0, 1, 0); STAGE_B(0, 0, 0); STAGE_B(0, 1, 0);
  STAGE_A(1, 0, 32); STAGE_A(1, 1, 32); STAGE_B(1, 0, 32); STAGE_B(1, 1, 32);

  const int hB = wc >> 1, rB = (wc & 1) * 64;
  for (int j = 0; j < 32; ++j) {
    const int p = j & 3;
    // entry wait: retire K-tile j's 4 unit-loads (oldest); K-tile j+1's stay in flight
    if (j == 31) asm volatile("s_waitcnt vmcnt(0)" ::: "memory");
    else         asm volatile("s_waitcnt vmcnt(4)" ::: "memory");
    __builtin_amdgcn_s_barrier();     // single sync per K-tile
    s16x8 b[4];
    #pragma unroll
    for (int m2 = 0; m2 < 2; ++m2) {
      s16x8 a[4];
      #pragma unroll
      for (int i = 0; i < 4; ++i) {
        const int ar = m2 * 64 + i * 16 + lrow;
        a[i] = *(const s16x8*)&smem.ring.As[p][wr][SWZ(ar)];
      }
      if (m2 == 0) {
        #pragma unroll
        for (int ni = 0; ni < 4; ++ni) {
          const int br = rB + ni * 16 + lrow;
          b[ni] = *(const s16x8*)&smem.ring.Bs[p][hB][SWZ(br)];
        }
      }
      if (j < 30) {               // stage K-tile j+2 into buf (j+2)&3 (last read at j-2)
        const int db = (j + 2) & 3, kn = (j + 2) * 32;
        if (m2 == 0) { STAGE_A(db, 0, kn); STAGE_A(db, 1, kn); }
        else         { STAGE_B(db, 0, kn); STAGE_B(db, 1, kn); }
      }
      __builtin_amdgcn_s_setprio(1);
      #pragma unroll
      for (int i = 0; i < 4; ++i)
        #pragma unroll
        for (int ni = 0; ni < 4; ++ni)
          acc[m2 * 4 + i][ni] =
              __builtin_amdgcn_mfma_f32_16x16x32_bf16(a[i], b[ni], acc[m2 * 4 + i][ni], 0, 0, 0);
      __builtin_amdgcn_s_setprio(0);
      // no trailing barrier: WAR carried by entry barriers (see header comment)
    }
  }
  #undef STAGE_A
  #undef STAGE_B
  #undef SWZ
  // ---- epilogue: acc -> LDS tile (bf16) -> coalesced ushort4 stores.
  __syncthreads();   // full fence: ring reads complete in ALL waves before tile overlay
  const int rbase = (l >> 4) * 4;
  const int trow0 = wr * 128, tcol0 = wc * 64;
  #pragma unroll
  for (int mi = 0; mi < 8; ++mi)
    #pragma unroll
    for (int ni = 0; ni < 4; ++ni)
      #pragma unroll
      for (int jj = 0; jj < 4; ++jj)
        smem.tile[trow0 + mi * 16 + rbase + jj][tcol0 + ni * 16 + lrow] = f2bf(acc[mi][ni][jj]);
  __syncthreads();
  #pragma unroll 1
  for (int q = t; q < 256 * 64; q += 512) {
    const int r = q >> 6;                 // row 0..255
    const int cl = (q & 63) * 4;          // local col chunk (4 u16)
    const int gcol = bn * 256 + cl;
    if (gcol < 1000) {
      ushort4 v = *(const ushort4*)&smem.tile[r][cl];   // 8-B aligned (row stride 520 B)
      *(ushort4*)&C[(size_t)(bm * 256 + r) * 1000 + gcol] = v;
    }
  }
}

// ---------------- k2: round-8/17 fused screen + serial exact rescore + inline probs.
__global__ __launch_bounds__(256) void k_topk(const float* __restrict__ feat,
                                              const float* __restrict__ prompts,
                                              const u16* __restrict__ sims,
                                              int2* __restrict__ resc,
                                              float2* __restrict__ resw,
                                              float* __restrict__ probs) {
  const int l = threadIdx.x & 63;
  const int row = blockIdx.x * 4 + (threadIdx.x >> 6);
  const u16* srow = sims + (size_t)row * 1000;
  const float NEG = -3.0e38f;
  float s[16];
  #pragma unroll
  for (int j = 0; j < 8; j++) {
    int c = 2 * l + 128 * j;
    if (c + 1 < 1000) {
      uint32_t v = *(const uint32_t*)(srow + c);
      s[2 * j] = bf2f((u16)(v & 0xFFFFu));
      s[2 * j + 1] = bf2f((u16)(v >> 16));
    } else {
      s[2 * j] = (c < 1000) ? bf2f(srow[c]) : NEG;
      s[2 * j + 1] = NEG;
    }
  }
  float a1 = NEG, a2 = NEG;
  #pragma unroll
  for (int j = 0; j < 16; j++) {
    float v = s[j];
    bool g1 = v > a1;
    a2 = g1 ? a1 : fmaxf(a2, v);
    a1 = g1 ? v : a1;
  }
  #pragma unroll
  for (int off = 32; off; off >>= 1) {
    float b1 = __shfl_xor(a1, off), b2 = __shfl_xor(a2, off);
    float m1 = fmaxf(a1, b1);
    float m2 = fmaxf(fminf(a1, b1), fmaxf(a2, b2));
    a1 = m1; a2 = m2;
  }
  const float T = a2 - 0.25f;   // stored-scale margin (round-8 analysis)
  uint32_t mask = 0;
  #pragma unroll
  for (int j = 0; j < 16; j++) {
    int c = 2 * l + 128 * (j >> 1) + (j & 1);
    if (c < 1000 && s[j] >= T) mask |= (1u << j);
  }
  const int base = l * 16;
  float q[16];
  const float4* fr = (const float4*)(feat + (size_t)row * 1024 + base);
  #pragma unroll
  for (int g = 0; g < 4; g++) {
    float4 x = fr[g];
    q[g * 4 + 0] = x.x; q[g * 4 + 1] = x.y; q[g * 4 + 2] = x.z; q[g * 4 + 3] = x.w;
  }
  float qq = 0.f;
  #pragma unroll
  for (int e = 0; e < 16; e++) qq += q[e] * q[e];
  #pragma unroll
  for (int off = 32; off; off >>= 1) qq += __shfl_xor(qq, off);
  float rn = 1.0f / fmaxf(sqrtf(qq), 1e-12f);
  float s1 = NEG, s2 = NEG;
  int c1 = 0x40000000, c2 = 0x40000000;
  while (true) {
    unsigned long long act = __ballot(mask != 0);
    if (!act) break;
    int ln = (int)__ffsll(act) - 1;
    int fj = __ffs(mask) - 1;
    int myc = 2 * l + 128 * ((fj >> 1) & 7) + (fj & 1);
    int bc = __shfl(myc, ln);
    if (l == ln) mask &= (mask - 1);
    bc = (bc < 1000) ? bc : 999;
    const float4* pr = (const float4*)(prompts + (size_t)bc * 1024 + base);
    float d = 0.f, nn = 0.f;
    #pragma unroll
    for (int g = 0; g < 4; g++) {
      float4 x = pr[g];
      d += q[g * 4 + 0] * x.x; d += q[g * 4 + 1] * x.y;
      d += q[g * 4 + 2] * x.z; d += q[g * 4 + 3] * x.w;
      nn += x.x * x.x + x.y * x.y + x.z * x.z + x.w * x.w;
    }
    #pragma unroll
    for (int off = 32; off; off >>= 1) {
      d += __shfl_xor(d, off);
      nn += __shfl_xor(nn, off);
    }
    float sc = d * rn / fmaxf(sqrtf(nn), 1e-12f);
    bool b1w = (sc > s1) || (sc == s1 && bc < c1);
    bool b2w = (sc > s2) || (sc == s2 && bc < c2);
    if (b1w) { s2 = s1; c2 = c1; s1 = sc; c1 = bc; }
    else if (b2w) { s2 = sc; c2 = bc; }
  }
  float e = expf(fminf(s2 - s1, 0.0f) * (1.0f / 0.07f));  // (0,1]
  float w1 = 1.0f / (1.0f + e);
  float w2 = e / (1.0f + e);
  float* prow = probs + (size_t)row * 1000;
  #pragma unroll
  for (int j = 0; j < 16; j++) {
    int c = l + 64 * j;
    if (c < 1000) prow[c] = (c == c1) ? w1 : ((c == c2) ? w2 : 0.0f);
  }
  if (l == 0) {
    resc[row] = make_int2(c1, c2);
    resw[row] = make_float2(w1, w2);
  }
}

// ---------------- k3: mixed = w1*P1 + w2*P2 (one block per row; overwrites dead sims scratch)
__global__ __launch_bounds__(256) void k_write2(const float* __restrict__ prompts,
                                                const int2* __restrict__ resc,
                                                const float2* __restrict__ resw,
                                                float* __restrict__ mixed) {
  const int row = blockIdx.x;
  const int t = threadIdx.x;
  int2 cc = resc[row];
  float2 ww = resw[row];
  float4 a = ((const float4*)(prompts + (size_t)cc.x * 1024))[t];
  float4 b = ((const float4*)(prompts + (size_t)cc.y * 1024))[t];
  float4 o;
  o.x = ww.x * a.x + ww.y * b.x;
  o.y = ww.x * a.y + ww.y * b.y;
  o.z = ww.x * a.z + ww.y * b.z;
  o.w = ww.x * a.w + ww.y * b.w;
  ((float4*)(mixed + (size_t)row * 1024))[t] = o;
}

extern "C" void kernel_launch(void* const* d_in, const int* in_sizes, int n_in,
                              void* d_out, int out_size, void* d_ws, size_t ws_size,
                              hipStream_t stream) {
  int fi = 0, pi = 1;
  for (int i = 0; i < n_in; i++) {
    if (in_sizes[i] == 67108864) fi = i;
    else if (in_sizes[i] == 1024000) pi = i;
  }
  const float* feat = (const float*)d_in[fi];
  const float* prompts = (const float*)d_in[pi];

  float* mixed = (float*)d_out;                 // [65536*1024] f32 (output 0)
  float* probs = mixed + 67108864ull;           // [65536*1000] f32 (output 1)

  // ws: [0,2MB) p_bf; [2,2.5MB) resc; [2.5,3MB) resw
  u16* p_bf = (u16*)d_ws;
  int2* resc = (int2*)((char*)d_ws + (2ull << 20));
  float2* resw = (float2*)((char*)d_ws + (2ull << 20) + (512ull << 10));

  // Memory plan (row-exclusive aliasing, stream-ordered):
  //   bf16 sims  at start of MIXED region (read by k_topk, overwritten by k_write2)
  //   bf16 feat  at start of PROBS region (read by k_sims, overwritten by k_topk's probs)
  u16* sims = (u16*)mixed;
  u16* feat_bf = (u16*)probs;

  hipLaunchKernelGGL(k_prep_prompts, dim3(1024), dim3(256), 0, stream, prompts, p_bf);
  hipLaunchKernelGGL(k_feat, dim3(2048), dim3(256), 0, stream, feat, feat_bf);
  hipLaunchKernelGGL(k_sims, dim3(1024), dim3(512), 0, stream, feat_bf, p_bf, sims);
  hipLaunchKernelGGL(k_topk, dim3(16384), dim3(256), 0, stream, feat, prompts, sims, resc, resw, probs);
  hipLaunchKernelGGL(k_write2, dim3(65536), dim3(256), 0, stream, prompts, resc, resw, mixed);
}